// Round 5
// baseline (34.048 us; speedup 1.0000x reference)
//
#include <hip/hip_runtime.h>
#include <math.h>

#define H1 1024
#define H2 512
#define NBLK 640            // 640 blocks x 4 waves = 2560 phase-1 wave-jobs
#define NSLOT 64
#define SLOT_STRIDE 16      // uints -> slots 64 B apart (no same-line atomic serialization)

// d_ws layout (bytes):
//   [0, 4096)    : 64 completion slots, 64 B apart
//   [4096, 4100) : done flag
//   [4608, ...)  : gh2 (1536 floats)
// memset clears [0, 4608) each launch.

__device__ __forceinline__ float sigmoidf_(float x) { return 1.0f / (1.0f + __expf(-x)); }
__device__ __forceinline__ float dot4(float4 a, float4 b) {
    return a.x * b.x + a.y * b.y + a.z * b.z + a.w * b.w;
}
__device__ __forceinline__ float wave_sum(float v) {
#pragma unroll
    for (int o = 32; o; o >>= 1) v += __shfl_xor(v, o, 64);
    return v;
}

__global__ __launch_bounds__(256, 4) void gru_one(
    const int* __restrict__ ids,
    const float* __restrict__ h1_in,
    const float* __restrict__ h2_in,
    const float* __restrict__ emb,
    const float* __restrict__ w_ih1,
    const float* __restrict__ w_hh1,
    const float* __restrict__ b_ih1,
    const float* __restrict__ b_hh1,
    const float* __restrict__ w_ih2,
    const float* __restrict__ w_hh2,
    const float* __restrict__ b_ih2,
    const float* __restrict__ b_hh2,
    float* __restrict__ d_out,
    unsigned int* __restrict__ ws_u)
{
    const int t = threadIdx.x;
    const int wid = t >> 6, lane = t & 63;
    const int b = blockIdx.x;
    const int g = b * 4 + wid;                 // global wave-job id [0, 2560)

    unsigned int* slots = ws_u;                 // slot i at ws_u[i*SLOT_STRIDE]
    unsigned int* dflag = ws_u + 1024;          // byte 4096
    float* gh2 = (float*)(ws_u + 1152);         // byte 4608, 1536 floats

    // ---------------- phase 1: wave-per-job ----------------
    if (g < H1) {
        // h1[j]: 6 dots of length 1024
        const int j = g;
        const float bxr = b_ih1[j], bxz = b_ih1[j + H1], bxn = b_ih1[j + 2 * H1];
        const float bhr = b_hh1[j], bhz = b_hh1[j + H1], bhn = b_hh1[j + 2 * H1];
        const float hprev = h1_in[j];
        const float* xrow = emb + (size_t)ids[0] * H1;
        float acc[6] = {0, 0, 0, 0, 0, 0};
#pragma unroll
        for (int k = 0; k < 4; ++k) {
            const int idx = lane + 64 * k;
            const float4 x4 = ((const float4*)xrow)[idx];
            const float4 h4 = ((const float4*)h1_in)[idx];
#pragma unroll
            for (int gg = 0; gg < 3; ++gg) {
                const float4 a = ((const float4*)(w_ih1 + (size_t)(gg * H1 + j) * H1))[idx];
                const float4 c = ((const float4*)(w_hh1 + (size_t)(gg * H1 + j) * H1))[idx];
                acc[gg]     += dot4(x4, a);
                acc[3 + gg] += dot4(h4, c);
            }
        }
#pragma unroll
        for (int gg = 0; gg < 6; ++gg) acc[gg] = wave_sum(acc[gg]);
        if (lane == 0) {
            const float r = sigmoidf_(acc[0] + bxr + acc[3] + bhr);
            const float z = sigmoidf_(acc[1] + bxz + acc[4] + bhz);
            const float n = tanhf(acc[2] + bxn + r * (acc[5] + bhn));
            const float h = (1.0f - z) * n + z * hprev;
            // publish at the chip-coherent point (bypasses non-coherent L2s)
            __hip_atomic_store(&d_out[H2 + j], h, __ATOMIC_RELAXED, __HIP_MEMORY_SCOPE_AGENT);
        }
    } else {
        // gh2[row] = h2_in . w_hh2[row] + b_hh2[row]
        const int row = g - H1;                // [0, 1536)
        const float bias = b_hh2[row];
        float acc = 0.0f;
#pragma unroll
        for (int k = 0; k < 2; ++k) {
            const int idx = lane + 64 * k;
            const float4 h4 = ((const float4*)h2_in)[idx];
            const float4 wv = ((const float4*)(w_hh2 + (size_t)row * H2))[idx];
            acc += dot4(h4, wv);
        }
        acc = wave_sum(acc);
        if (lane == 0)
            __hip_atomic_store(&gh2[row], acc + bias, __ATOMIC_RELAXED, __HIP_MEMORY_SCOPE_AGENT);
    }

    // ---------------- completion count ----------------
    asm volatile("s_waitcnt vmcnt(0)" ::: "memory");   // own wave's atomic store is globally done
    __syncthreads();                                    // all 4 waves of this block done
    if (t == 0)
        __hip_atomic_fetch_add(&slots[(b & (NSLOT - 1)) * SLOT_STRIDE], 1u,
                               __ATOMIC_RELAXED, __HIP_MEMORY_SCOPE_AGENT);
    if (b >= H2) return;                                // no phase-2 job: free the CU slot

    // ---------------- barrier: 8 redundant checkers + relaxed spin ----------------
    if (b < 8 && t == 0) {
        for (;;) {
            unsigned s = 0;
#pragma unroll 1
            for (int i = 0; i < NSLOT; ++i)
                s += __hip_atomic_load(&slots[i * SLOT_STRIDE],
                                       __ATOMIC_RELAXED, __HIP_MEMORY_SCOPE_AGENT);
            if (s == (unsigned)NBLK) break;
            __builtin_amdgcn_s_sleep(8);
        }
        __hip_atomic_store(dflag, 1u, __ATOMIC_RELAXED, __HIP_MEMORY_SCOPE_AGENT);
    }
    if (t == 0) {
        while (__hip_atomic_load(dflag, __ATOMIC_RELAXED, __HIP_MEMORY_SCOPE_AGENT) == 0u)
            __builtin_amdgcn_s_sleep(4);
    }
    __syncthreads();

    // ---------------- phase 2: block-per-output, j = b ----------------
    __shared__ float red[3][4];
    __shared__ float shg[3];
    const int j = b;                                   // [0, 512)
    const float bxr2 = b_ih2[j], bxz2 = b_ih2[j + H2], bxn2 = b_ih2[j + 2 * H2];
    const float hprev2 = h2_in[j];
    if (t < 3)
        shg[t] = __hip_atomic_load(&gh2[j + H2 * t], __ATOMIC_RELAXED, __HIP_MEMORY_SCOPE_AGENT);

    // h1 gather through the coherent point: 2x 8-byte atomic loads per thread
    unsigned long long* h1u = (unsigned long long*)(d_out + H2);
    const unsigned long long u0 =
        __hip_atomic_load(&h1u[2 * t + 0], __ATOMIC_RELAXED, __HIP_MEMORY_SCOPE_AGENT);
    const unsigned long long u1 =
        __hip_atomic_load(&h1u[2 * t + 1], __ATOMIC_RELAXED, __HIP_MEMORY_SCOPE_AGENT);
    union { unsigned long long u; float f[2]; } c0, c1;
    c0.u = u0; c1.u = u1;
    const float4 hh = make_float4(c0.f[0], c0.f[1], c1.f[0], c1.f[1]);

    float a3[3];
#pragma unroll
    for (int gg = 0; gg < 3; ++gg) {
        const float4 a = ((const float4*)(w_ih2 + (size_t)(gg * H2 + j) * H1))[t];
        a3[gg] = dot4(hh, a);   // weights never written -> cached loads are safe
    }
#pragma unroll
    for (int gg = 0; gg < 3; ++gg) {
        const float v = wave_sum(a3[gg]);
        if (lane == 0) red[gg][wid] = v;
    }
    __syncthreads();
    if (t == 0) {
        const float gx0 = red[0][0] + red[0][1] + red[0][2] + red[0][3];
        const float gx1 = red[1][0] + red[1][1] + red[1][2] + red[1][3];
        const float gx2 = red[2][0] + red[2][1] + red[2][2] + red[2][3];
        const float r = sigmoidf_(gx0 + bxr2 + shg[0]);
        const float z = sigmoidf_(gx1 + bxz2 + shg[1]);
        const float n = tanhf(gx2 + bxn2 + r * shg[2]);
        const float h = (1.0f - z) * n + z * hprev2;
        d_out[j] = h;                // output (== h2)
        d_out[3 * H2 + j] = h;       // h2 at flat offset 1536
    }
}

extern "C" void kernel_launch(void* const* d_in, const int* in_sizes, int n_in,
                              void* d_out, int out_size, void* d_ws, size_t ws_size,
                              hipStream_t stream) {
    const int*   ids   = (const int*)d_in[0];
    const float* h1_in = (const float*)d_in[1];
    const float* h2_in = (const float*)d_in[2];
    const float* emb   = (const float*)d_in[3];
    const float* w_ih1 = (const float*)d_in[4];
    const float* w_hh1 = (const float*)d_in[5];
    const float* b_ih1 = (const float*)d_in[6];
    const float* b_hh1 = (const float*)d_in[7];
    const float* w_ih2 = (const float*)d_in[8];
    const float* w_hh2 = (const float*)d_in[9];
    const float* b_ih2 = (const float*)d_in[10];
    const float* b_hh2 = (const float*)d_in[11];

    hipMemsetAsync(d_ws, 0, 4608, stream);   // clear slots + done flag every launch
    gru_one<<<NBLK, 256, 0, stream>>>(ids, h1_in, h2_in, emb,
                                      w_ih1, w_hh1, b_ih1, b_hh1,
                                      w_ih2, w_hh2, b_ih2, b_hh2,
                                      (float*)d_out, (unsigned int*)d_ws);
}

// Round 7
// 13.304 us; speedup vs baseline: 2.5593x; 2.5593x over previous
//
#include <hip/hip_runtime.h>
#include <math.h>

#define H1 1024
#define H2 512

typedef float vfloat4 __attribute__((ext_vector_type(4)));
typedef float vfloat2 __attribute__((ext_vector_type(2)));

__device__ __forceinline__ float sigmoidf_(float x) { return 1.0f / (1.0f + __expf(-x)); }
__device__ __forceinline__ float dot4(float4 a, vfloat4 b) {
    return a.x * b.x + a.y * b.y + a.z * b.z + a.w * b.w;
}
__device__ __forceinline__ float wave_sum(float v) {
#pragma unroll
    for (int o = 32; o; o >>= 1) v += __shfl_xor(v, o, 64);
    return v;
}
__device__ __forceinline__ vfloat4 ntload4(const float* p) {
    return __builtin_nontemporal_load((const vfloat4*)p);
}
__device__ __forceinline__ vfloat2 ntload2(const float* p) {
    return __builtin_nontemporal_load((const vfloat2*)p);
}

// Kernel 1: h1 only. Exactly 256 blocks (1 per CU), 4 waves each, wave-per-output.
// Each wave: 6 dots of length 1024 (3 vs emb row, 3 vs h1_in). 25.2 MB of weights.
__global__ __launch_bounds__(256) void gru_k1(
    const int* __restrict__ ids,
    const float* __restrict__ h1_in,
    const float* __restrict__ emb,
    const float* __restrict__ w_ih1,
    const float* __restrict__ w_hh1,
    const float* __restrict__ b_ih1,
    const float* __restrict__ b_hh1,
    float* __restrict__ d_out)
{
    const int lane = threadIdx.x & 63;
    const int j = blockIdx.x * 4 + (threadIdx.x >> 6);   // [0, 1024)

    // Hoisted uniform scalars — overlap the streaming loop.
    const float bxr = b_ih1[j], bxz = b_ih1[j + H1], bxn = b_ih1[j + 2 * H1];
    const float bhr = b_hh1[j], bhz = b_hh1[j + H1], bhn = b_hh1[j + 2 * H1];
    const float hprev = h1_in[j];
    const float* xrow = emb + (size_t)ids[0] * H1;

    float acc[6] = {0, 0, 0, 0, 0, 0};
#pragma unroll
    for (int k = 0; k < 4; ++k) {
        const int idx = lane + 64 * k;                   // 256 float4 = 1024 floats
        const float4 x4 = ((const float4*)xrow)[idx];
        const float4 h4 = ((const float4*)h1_in)[idx];
#pragma unroll
        for (int g = 0; g < 3; ++g) {
            const vfloat4 a = ntload4(w_ih1 + (size_t)(g * H1 + j) * H1 + 4 * idx);
            const vfloat4 c = ntload4(w_hh1 + (size_t)(g * H1 + j) * H1 + 4 * idx);
            acc[g]     += dot4(x4, a);
            acc[3 + g] += dot4(h4, c);
        }
    }
#pragma unroll
    for (int g = 0; g < 6; ++g) acc[g] = wave_sum(acc[g]);
    if (lane == 0) {
        const float r = sigmoidf_(acc[0] + bxr + acc[3] + bhr);
        const float z = sigmoidf_(acc[1] + bxz + acc[4] + bhz);
        const float n = tanhf(acc[2] + bxn + r * (acc[5] + bhn));
        d_out[H2 + j] = (1.0f - z) * n + z * hprev;      // h1 at flat offset 512
    }
}

// Kernel 2: full layer-2 cell. Exactly 512 blocks (2 per CU), block-per-output.
// Block j: 3 dots of length 1024 (w_ih2 rows vs h1) + 3 dots of length 512
// (w_hh2 rows vs h2_in). 9.4 MB of weights spread over all 256 CUs.
__global__ __launch_bounds__(256) void gru_k2(
    const float* __restrict__ h2_in,
    const float* __restrict__ w_ih2,
    const float* __restrict__ w_hh2,
    const float* __restrict__ b_ih2,
    const float* __restrict__ b_hh2,
    float* __restrict__ d_out)
{
    __shared__ float red[6][4];
    const int t = threadIdx.x;
    const int wid = t >> 6, lane = t & 63;
    const int j = blockIdx.x;                             // [0, 512)

    // Hoisted uniform scalars.
    const float bxr = b_ih2[j], bxz = b_ih2[j + H2], bxn = b_ih2[j + 2 * H2];
    const float bhr = b_hh2[j], bhz = b_hh2[j + H2], bhn = b_hh2[j + 2 * H2];
    const float hprev = h2_in[j];

    const float* h1v = d_out + H2;                        // written by gru_k1
    const float4 hh = ((const float4*)h1v)[t];            // 256 float4 = 1024 floats
    const float2 h2v = ((const float2*)h2_in)[t];         // 256 float2 = 512 floats

    float acc[6];
#pragma unroll
    for (int g = 0; g < 3; ++g) {
        const vfloat4 a = ntload4(w_ih2 + (size_t)(g * H2 + j) * H1 + 4 * t);
        const vfloat2 c = ntload2(w_hh2 + (size_t)(g * H2 + j) * H2 + 2 * t);
        acc[g]     = dot4(hh, a);
        acc[3 + g] = h2v.x * c.x + h2v.y * c.y;
    }
#pragma unroll
    for (int g = 0; g < 6; ++g) {
        const float v = wave_sum(acc[g]);
        if (lane == 0) red[g][wid] = v;
    }
    __syncthreads();
    if (t == 0) {
        float s[6];
#pragma unroll
        for (int g = 0; g < 6; ++g)
            s[g] = red[g][0] + red[g][1] + red[g][2] + red[g][3];
        const float r = sigmoidf_(s[0] + bxr + s[3] + bhr);
        const float z = sigmoidf_(s[1] + bxz + s[4] + bhz);
        const float n = tanhf(s[2] + bxn + r * (s[5] + bhn));
        const float h = (1.0f - z) * n + z * hprev;
        d_out[j] = h;                // output (== h2)
        d_out[3 * H2 + j] = h;       // h2 at flat offset 1536
    }
}

extern "C" void kernel_launch(void* const* d_in, const int* in_sizes, int n_in,
                              void* d_out, int out_size, void* d_ws, size_t ws_size,
                              hipStream_t stream) {
    const int*   ids   = (const int*)d_in[0];
    const float* h1_in = (const float*)d_in[1];
    const float* h2_in = (const float*)d_in[2];
    const float* emb   = (const float*)d_in[3];
    const float* w_ih1 = (const float*)d_in[4];
    const float* w_hh1 = (const float*)d_in[5];
    const float* b_ih1 = (const float*)d_in[6];
    const float* b_hh1 = (const float*)d_in[7];
    const float* w_ih2 = (const float*)d_in[8];
    const float* w_hh2 = (const float*)d_in[9];
    const float* b_ih2 = (const float*)d_in[10];
    const float* b_hh2 = (const float*)d_in[11];
    float* out = (float*)d_out;

    gru_k1<<<H1 / 4, 256, 0, stream>>>(ids, h1_in, emb, w_ih1, w_hh1, b_ih1, b_hh1, out);
    gru_k2<<<H2, 256, 0, stream>>>(h2_in, w_ih2, w_hh2, b_ih2, b_hh2, out);
}